// Round 4
// baseline (387.654 us; speedup 1.0000x reference)
//
#include <hip/hip_runtime.h>
#include <cstdint>
#include <cstddef>

// Problem constants (fixed by the reference)
#define NN 16384      // nodes
#define DIN 1024      // hid_size
#define DMID 1500     // hidden_size (logical)
#define DMIDP 1536    // padded to multiple of 256
#define NE 131072     // edges

typedef __bf16 bf16;
typedef __bf16 bf16x4 __attribute__((ext_vector_type(4)));
typedef __bf16 bf16x8 __attribute__((ext_vector_type(8)));
typedef float f32x4 __attribute__((ext_vector_type(4)));

#define GLOBAL_AS __attribute__((address_space(1)))
#define LDS_AS __attribute__((address_space(3)))

__device__ __forceinline__ void gload_lds16(const bf16* g, bf16* l) {
    // async 16B/lane global->LDS; LDS dest is wave-uniform base + lane*16
    __builtin_amdgcn_global_load_lds((GLOBAL_AS const unsigned int*)(g),
                                     (LDS_AS unsigned int*)(l), 16, 0, 0);
}

#define SBAR() asm volatile("s_barrier" ::: "memory")
#define WAITV_(N) asm volatile("s_waitcnt vmcnt(" #N ")" ::: "memory")
#define WAITV(N) WAITV_(N)
#define WAITL0() asm volatile("s_waitcnt lgkmcnt(0)" ::: "memory")

// ---------------- CSR build + normalization ----------------
__global__ void k_zero_cnt(int* cnt) {
    cnt[blockIdx.x * 256 + threadIdx.x] = 0;
}

__global__ void k_count(const int* __restrict__ dst, int* cnt) {
    int e = blockIdx.x * 256 + threadIdx.x;
    atomicAdd(&cnt[dst[e]], 1);
}

// single block, 1024 threads, 16 nodes each.
// rowptr = exclusive scan of PADDED counts (pad to multiple of 8); cursor = start; isd.
__global__ __launch_bounds__(1024) void k_scan(const int* __restrict__ cnt,
                                               int* __restrict__ rowptr,
                                               int* __restrict__ cursor,
                                               float* __restrict__ isd) {
    __shared__ int sums[1024];
    int t = threadIdx.x;
    int base = t * 16;
    int v[16], p[16];
    int s = 0;
#pragma unroll
    for (int k = 0; k < 16; ++k) {
        v[k] = cnt[base + k];
        p[k] = (v[k] + 7) & ~7;  // padded row length (multiple of 8)
        s += p[k];
    }
    sums[t] = s;
    __syncthreads();
    for (int off = 1; off < 1024; off <<= 1) {
        int y = (t >= off) ? sums[t - off] : 0;
        __syncthreads();
        sums[t] += y;
        __syncthreads();
    }
    int run = sums[t] - s;  // exclusive prefix
#pragma unroll
    for (int k = 0; k < 16; ++k) {
        rowptr[base + k] = run;
        cursor[base + k] = run;
        isd[base + k] = rsqrtf((float)(v[k] + 1));  // +1 self-loop
        run += p[k];
    }
    if (t == 1023) rowptr[NN] = run;
}

__global__ void k_fill(const int* __restrict__ src, const int* __restrict__ dst,
                       int* cursor, const float* __restrict__ isd,
                       int* __restrict__ csr_src, float* __restrict__ csr_w) {
    int e = blockIdx.x * 256 + threadIdx.x;
    int s = src[e], d = dst[e];
    int pos = atomicAdd(&cursor[d], 1);
    csr_src[pos] = s;
    csr_w[pos] = isd[s] * isd[d];
}

// fill pad slots: src = self (L1-hot row), w = 0 (contributes nothing)
__global__ void k_pad(const int* __restrict__ cnt, const int* __restrict__ rowptr,
                      int* __restrict__ csr_src, float* __restrict__ csr_w) {
    int i = blockIdx.x * 256 + threadIdx.x;
    int c = cnt[i];
    int p = (c + 7) & ~7;
    int base = rowptr[i];
    for (int q = c; q < p; ++q) {
        csr_src[base + q] = i;
        csr_w[base + q] = 0.0f;
    }
}

// ---------------- conversions ----------------
__global__ void k_cvt_x(const float4* __restrict__ x, bf16x4* __restrict__ xb) {
    int i = blockIdx.x * 256 + threadIdx.x;  // NN*DIN/4 total
    float4 v = x[i];
    bf16x4 o;
    o[0] = (bf16)v.x; o[1] = (bf16)v.y; o[2] = (bf16)v.z; o[3] = (bf16)v.w;
    xb[i] = o;
}

// W1 [1024][1500] f32 row-major -> W1b [1536][1024] bf16 (transposed, n-pad zero)
__global__ void k_cvt_w1(const float* __restrict__ W1, bf16* __restrict__ W1b) {
    int n = blockIdx.x;  // 0..1535
    for (int k = threadIdx.x; k < DIN; k += 256)
        W1b[n * DIN + k] = (n < DMID) ? (bf16)W1[(size_t)k * DMID + n] : (bf16)0.0f;
}

// W2 [1500][1024] f32 row-major -> W2b [1024][1536] bf16 (transposed, k-pad zero)
__global__ void k_cvt_w2(const float* __restrict__ W2, bf16* __restrict__ W2b) {
    int n = blockIdx.x;  // 0..1023
    for (int k = threadIdx.x; k < DMIDP; k += 256)
        W2b[n * DMIDP + k] = (k < DMID) ? (bf16)W2[(size_t)k * DIN + n] : (bf16)0.0f;
}

// ---------------- GEMM: C[M,N] = A[M,K] @ Bt[N,K]^T, bf16 in / bf16 out ----------------
// 256x256 tile, BK=64, 8 waves (2M x 4N), per-wave 128x64 output.
// R4: faithful 8-phase schedule (m194-m201 template). R1-R3 post-mortem: three
// sync structures all pinned at 666-677 TF = the 2-phase anchor (m248v2),
// because staging was boundary-clustered. m196 isolated the lever: per-phase
// ds_read ∥ global_load_lds ∥ MFMA interleave. Here:
//  - 4 phases per K-tile, quadrant (mh,nh) per phase, 16 MFMA each.
//    Reads: q1 = 8A+4B, q2 = 4B, q3 = 8A, q4 = 0 (A reused across nh, B across mh).
//  - one half-tile staged per phase (2 gloads/wave):
//    q1:(Y+1).Atop->buf c^1   [c^1.Atop last read at group Y-1 q3; barrier-cert]
//    q2:(Y+1).Abot->buf c^1
//    q3:(Y+2).Btop->buf c     [c.Btop last read q2 this group; q2-end barrier-cert]
//    q4:(Y+2).Bbot->buf c
//  - counted vmcnt(4) once per K-tile at q4: certifies (Y+1).A (read next q1),
//    leaves (Y+2).B's 4 loads in flight. Tail: vmcnt(0) when stages skipped.
//  - each phase: reads; stage; SBAR; lgkm(0); setprio(1) MFMA setprio(0); SBAR.
//    The lgkm(0)+end-barrier pair is the cross-wave WAR finalizer for restaging.
// T2 XOR swizzle kept (conflicts measured 0 since R1).
template <int K, int N, bool RELU_BIAS>
__global__ __launch_bounds__(512, 2) void gemm256(const bf16* __restrict__ A,
                                                  const bf16* __restrict__ Bt,
                                                  bf16* __restrict__ C,
                                                  const float* __restrict__ bias) {
    constexpr int NT = K / 64;
    __shared__ __align__(16) bf16 lds[2][2][256 * 64];  // [buf][A/B] = 128 KB
    const int tid = threadIdx.x;
    const int w = tid >> 6;
    const int lane = tid & 63;
    const int bm = blockIdx.x, bn = blockIdx.y;
    const int fr = lane & 15, fq = lane >> 4;
    const int wm = w >> 2;   // 0..1 : M half (128 rows)
    const int wn = w & 3;    // 0..3 : N quarter (64 cols)
    const int sx = fr & 7;   // read-side swizzle mask

    // staging: lane l covers row_local = l>>3 in each 8-row gload; fetch global
    // slot (l&7)^(l>>3) so the linear LDS write lands pre-swizzled (rule #21).
    const int lrow = lane >> 3;
    const int lslot = (lane & 7) ^ lrow;
    const bf16* gA = A + (size_t)(bm * 256 + lrow) * K + lslot * 8;
    const bf16* gB = Bt + (size_t)(bn * 256 + lrow) * K + lslot * 8;

    f32x4 acc[8][4];
#pragma unroll
    for (int i = 0; i < 8; ++i)
#pragma unroll
        for (int j = 0; j < 4; ++j) acc[i][j] = {0.f, 0.f, 0.f, 0.f};

// stage one half-tile (2 gloads/wave): MAT 0=A 1=B, HALF 0=rows0-127 1=rows128-255
// wave w covers rows HALF*128 + w*16 .. +15 (two 8-row gloads)
#define STAGEH(T, BUF, MAT, HALF)                                              \
    do {                                                                       \
        const bf16* _g = (MAT) ? gB : gA;                                      \
        bf16* _l = &lds[BUF][MAT][0] + ((HALF) * 128 + w * 16) * 64;           \
        _Pragma("unroll") for (int r = 0; r < 2; ++r)                          \
            gload_lds16(_g + (size_t)((HALF) * 128 + w * 16 + r * 8) * K       \
                           + (size_t)(T) * 64,                                 \
                        _l + r * 512);                                         \
    } while (0)

// ds_read the A-subtile for M-half MH (8 frags: mt4 x ks2) / B for N-half NH (4)
#define LDA8(DST, BUF, MH)                                                     \
    _Pragma("unroll") for (int mt = 0; mt < 4; ++mt)                           \
    _Pragma("unroll") for (int ks = 0; ks < 2; ++ks) {                         \
        int row = wm * 128 + (MH) * 64 + mt * 16 + fr;                         \
        int sl = ((ks << 2) | fq) ^ sx;                                        \
        DST[mt][ks] = *(const bf16x8*)((const char*)&lds[BUF][0][0] +          \
                                       row * 128 + sl * 16);                   \
    }
#define LDB4(DST, BUF, NH)                                                     \
    _Pragma("unroll") for (int nt = 0; nt < 2; ++nt)                           \
    _Pragma("unroll") for (int ks = 0; ks < 2; ++ks) {                         \
        int row = wn * 64 + (NH) * 32 + nt * 16 + fr;                          \
        int sl = ((ks << 2) | fq) ^ sx;                                        \
        DST[nt][ks] = *(const bf16x8*)((const char*)&lds[BUF][1][0] +          \
                                       row * 128 + sl * 16);                   \
    }
#define MFMA16(MH, NH, AF, BF)                                                 \
    __builtin_amdgcn_s_setprio(1);                                             \
    _Pragma("unroll") for (int mt = 0; mt < 4; ++mt)                           \
    _Pragma("unroll") for (int nt = 0; nt < 2; ++nt)                           \
    _Pragma("unroll") for (int ks = 0; ks < 2; ++ks)                           \
        acc[(MH) * 4 + mt][(NH) * 2 + nt] =                                    \
            __builtin_amdgcn_mfma_f32_16x16x32_bf16(                           \
                AF[mt][ks], BF[nt][ks], acc[(MH) * 4 + mt][(NH) * 2 + nt],     \
                0, 0, 0);                                                      \
    __builtin_amdgcn_s_setprio(0);

    // prologue: tile0 all 4 halves + tile1's B halves (12 gloads in flight);
    // vmcnt(4) certifies tile0, leaves tile1.B's 4 loads outstanding.
    STAGEH(0, 0, 0, 0); STAGEH(0, 0, 0, 1);
    STAGEH(0, 0, 1, 0); STAGEH(0, 0, 1, 1);
    STAGEH(1, 1, 1, 0); STAGEH(1, 1, 1, 1);
    WAITV(4);
    SBAR();

    bf16x8 a[4][2], b0[2][2], b1[2][2];
#pragma unroll 2
    for (int t = 0; t < NT; ++t) {
        const int c = t & 1;
        // q1: (mh0,nh0) + stage (t+1).Atop
        LDA8(a, c, 0);
        LDB4(b0, c, 0);
        if (t + 1 < NT) STAGEH(t + 1, c ^ 1, 0, 0);
        SBAR(); WAITL0();
        MFMA16(0, 0, a, b0);
        SBAR();
        // q2: (mh0,nh1) + stage (t+1).Abot
        LDB4(b1, c, 1);
        if (t + 1 < NT) STAGEH(t + 1, c ^ 1, 0, 1);
        SBAR(); WAITL0();
        MFMA16(0, 1, a, b1);
        SBAR();
        // q3: (mh1,nh0) + stage (t+2).Btop (c.Btop freed by q2-end barrier)
        LDA8(a, c, 1);
        if (t + 2 < NT) STAGEH(t + 2, c, 1, 0);
        SBAR(); WAITL0();
        MFMA16(1, 0, a, b0);
        SBAR();
        // q4: (mh1,nh1) + stage (t+2).Bbot + the per-K-tile counted checkpoint
        if (t + 2 < NT) {
            STAGEH(t + 2, c, 1, 1);
            WAITV(4);   // certifies (t+1).A halves; (t+2).B stays in flight
        } else {
            WAITV(0);   // tail: stages skipped -> certify everything
        }
        SBAR();
        MFMA16(1, 1, a, b1);
        SBAR();
    }
#undef STAGEH
#undef LDA8
#undef LDB4
#undef MFMA16

    // epilogue: C/D layout (verified m89/m91): col = lane&15, row = (lane>>4)*4 + reg
    float bv[4];
    if (RELU_BIAS) {
#pragma unroll
        for (int nt = 0; nt < 4; ++nt) {
            int col = bn * 256 + wn * 64 + nt * 16 + fr;
            bv[nt] = (col < DMID) ? bias[col] : 0.0f;
        }
    }
#pragma unroll
    for (int mq = 0; mq < 8; ++mq) {
        int row0 = bm * 256 + wm * 128 + mq * 16 + fq * 4;
#pragma unroll
        for (int nt = 0; nt < 4; ++nt) {
            int col = bn * 256 + wn * 64 + nt * 16 + fr;
#pragma unroll
            for (int r = 0; r < 4; ++r) {
                float v = acc[mq][nt][r];
                if (RELU_BIAS) v = fmaxf(v + bv[nt], 0.0f);
                C[(size_t)(row0 + r) * N + col] = (bf16)v;
            }
        }
    }
}

// ---------------- aggregation (CSR gather, barrier-free) ----------------
// XA[i] = isd_i^2 * X[i] + sum_j w_ij * X[j], 1024-wide bf16 in/out
__global__ __launch_bounds__(128) void k_aggX(const bf16* __restrict__ X,
                                              const int* __restrict__ rowptr,
                                              const int* __restrict__ csr_src,
                                              const float* __restrict__ csr_w,
                                              const float* __restrict__ isd,
                                              bf16* __restrict__ XA) {
    int i = blockIdx.x;
    int t = threadIdx.x;      // 128 threads * 8 cols = 1024
    int c0 = t * 8;
    int beg = rowptr[i], end = rowptr[i + 1];  // uniform; (end-beg) % 8 == 0
    float wi = isd[i];
    float w0 = wi * wi;
    float a[8];
    bf16x8 h = *(const bf16x8*)&X[(size_t)i * DIN + c0];
#pragma unroll
    for (int k = 0; k < 8; ++k) a[k] = w0 * (float)h[k];
    for (int e = beg; e < end; e += 8) {
        int j[8];
        float w[8];
        bf16x8 hv[8];
#pragma unroll
        for (int q = 0; q < 8; ++q) { j[q] = csr_src[e + q]; w[q] = csr_w[e + q]; }
#pragma unroll
        for (int q = 0; q < 8; ++q)
            hv[q] = *(const bf16x8*)&X[(size_t)j[q] * DIN + c0];
#pragma unroll
        for (int q = 0; q < 8; ++q)
#pragma unroll
            for (int k = 0; k < 8; ++k) a[k] += w[q] * (float)hv[q][k];
    }
    bf16x8 o;
#pragma unroll
    for (int k = 0; k < 8; ++k) o[k] = (bf16)a[k];
    *(bf16x8*)&XA[(size_t)i * DIN + c0] = o;
}

// layer 2: out[i] = isd_i^2 * H[i] + sum_j w_ij * H[j] + b2, f32 out
__global__ __launch_bounds__(128) void k_agg2(const bf16* __restrict__ H,
                                              const int* __restrict__ rowptr,
                                              const int* __restrict__ csr_src,
                                              const float* __restrict__ csr_w,
                                              const float* __restrict__ isd,
                                              const float* __restrict__ b2,
                                              float* __restrict__ out) {
    int i = blockIdx.x;
    int t = threadIdx.x;      // 128 threads * 8 cols = 1024
    int c0 = t * 8;
    int beg = rowptr[i], end = rowptr[i + 1];
    float wi = isd[i];
    float w0 = wi * wi;
    float a[8];
    bf16x8 h = *(const bf16x8*)&H[(size_t)i * DIN + c0];
#pragma unroll
    for (int k = 0; k < 8; ++k) a[k] = w0 * (float)h[k];
    for (int e = beg; e < end; e += 8) {
        int j[8];
        float w[8];
        bf16x8 hv[8];
#pragma unroll
        for (int q = 0; q < 8; ++q) { j[q] = csr_src[e + q]; w[q] = csr_w[e + q]; }
#pragma unroll
        for (int q = 0; q < 8; ++q)
            hv[q] = *(const bf16x8*)&H[(size_t)j[q] * DIN + c0];
#pragma unroll
        for (int q = 0; q < 8; ++q)
#pragma unroll
            for (int k = 0; k < 8; ++k) a[k] += w[q] * (float)hv[q][k];
    }
    float4 o0, o1;
    o0.x = a[0] + b2[c0 + 0]; o0.y = a[1] + b2[c0 + 1];
    o0.z = a[2] + b2[c0 + 2]; o0.w = a[3] + b2[c0 + 3];
    o1.x = a[4] + b2[c0 + 4]; o1.y = a[5] + b2[c0 + 5];
    o1.z = a[6] + b2[c0 + 6]; o1.w = a[7] + b2[c0 + 7];
    *(float4*)&out[(size_t)i * DIN + c0] = o0;
    *(float4*)&out[(size_t)i * DIN + c0 + 4] = o1;
}

extern "C" void kernel_launch(void* const* d_in, const int* in_sizes, int n_in,
                              void* d_out, int out_size, void* d_ws, size_t ws_size,
                              hipStream_t stream) {
    const float* x = (const float*)d_in[0];
    const int* ei = (const int*)d_in[1];
    const float* W1 = (const float*)d_in[2];
    const float* b1 = (const float*)d_in[3];
    const float* W2 = (const float*)d_in[4];
    const float* b2 = (const float*)d_in[5];
    float* out = (float*)d_out;
    const int* src = ei;
    const int* dst = ei + NE;

    // workspace layout (bytes), total ~122 MB
    char* ws = (char*)d_ws;
    int* cnt      = (int*)(ws + 0);          //  64 KB
    int* cursor   = (int*)(ws + 65536);      //  64 KB
    float* isd    = (float*)(ws + 131072);   //  64 KB
    int* rowptr   = (int*)(ws + 196608);     // 128 KB (NN+1 ints)
    int* csr_src  = (int*)(ws + 327680);     //   2 MB (padded <= 245760 entries)
    float* csr_w  = (float*)(ws + 2424832);  //   2 MB
    bf16* Xb      = (bf16*)(ws + 4521984);   // 33.55 MB (16384x1024)
    bf16* XA      = (bf16*)(ws + 38076416);  // 33.55 MB — reused as H2b
    bf16* W1b     = (bf16*)(ws + 71630848);  //  3.15 MB (1536x1024, transposed)
    bf16* W2b     = (bf16*)(ws + 74776576);  //  3.15 MB (1024x1536, transposed)
    bf16* Y1b     = (bf16*)(ws + 77922304);  // 50.33 MB (16384x1536)
    bf16* H2b     = XA;                      // XA dead after GEMM1

    // CSR + normalization
    k_zero_cnt<<<NN / 256, 256, 0, stream>>>(cnt);
    k_count<<<NE / 256, 256, 0, stream>>>(dst, cnt);
    k_scan<<<1, 1024, 0, stream>>>(cnt, rowptr, cursor, isd);
    k_fill<<<NE / 256, 256, 0, stream>>>(src, dst, cursor, isd, csr_src, csr_w);
    k_pad<<<NN / 256, 256, 0, stream>>>(cnt, rowptr, csr_src, csr_w);

    // bf16 conversions
    k_cvt_x<<<NN * DIN / 4 / 256, 256, 0, stream>>>((const float4*)x, (bf16x4*)Xb);
    k_cvt_w1<<<DMIDP, 256, 0, stream>>>(W1, W1b);
    k_cvt_w2<<<DIN, 256, 0, stream>>>(W2, W2b);

    // layer 1: XA = A_hat @ X ; Y1 = relu(XA @ W1 + b1)   [agg commutes with linear]
    k_aggX<<<NN, 128, 0, stream>>>(Xb, rowptr, csr_src, csr_w, isd, XA);
    dim3 g1(NN / 256, DMIDP / 256);
    gemm256<DIN, DMIDP, true><<<g1, 512, 0, stream>>>(XA, W1b, Y1b, b1);

    // layer 2: H2 = Y1 @ W2 ; out = A_hat @ H2 + b2
    dim3 g2(NN / 256, DIN / 256);
    gemm256<DMIDP, DIN, false><<<g2, 512, 0, stream>>>(Y1b, W2b, H2b, nullptr);
    k_agg2<<<NN, 128, 0, stream>>>(H2b, rowptr, csr_src, csr_w, isd, b2, out);
}